// Round 5
// baseline (232.903 us; speedup 1.0000x reference)
//
#include <hip/hip_runtime.h>
#include <hip/hip_bf16.h>

#define N_ROWS 8192
#define NZ 16384           // rows of Z = [An; Bn]
#define DIM 256
#define TAU_INV 2.0f
#define BT 128             // block tile (square)
#define BK 64
#define NTILE 128          // NZ / BT
#define NTRI (NTILE * (NTILE + 1) / 2)   // 8256 upper-tri blocks

typedef float f32x4 __attribute__((ext_vector_type(4)));
typedef short bf16x8 __attribute__((ext_vector_type(8)));

// ---------------------------------------------------------------------------
// Kernel 1: one WAVE per row. L2-normalize z1,z2 rows -> bf16 Zn (An rows
// 0..8191, Bn rows 8192..16383); pos[i] = dot of the QUANTIZED an_i,bn_i.
// Also zeroes S (used only by the atomic fallback path; cheap).
// ---------------------------------------------------------------------------
__global__ __launch_bounds__(256) void normalize_kernel(
    const float* __restrict__ z1, const float* __restrict__ z2,
    __hip_bfloat16* __restrict__ Zn, float* __restrict__ pos,
    float* __restrict__ Szero)
{
    const int tid = threadIdx.x;
    if (blockIdx.x < 64) Szero[blockIdx.x * 256 + tid] = 0.0f;  // 64*256=16384

    const int wave = tid >> 6;
    const int lane = tid & 63;
    const int row = blockIdx.x * 4 + wave;      // 0..8191

    const float4 a = ((const float4*)(z1 + (size_t)row * DIM))[lane];
    const float4 b = ((const float4*)(z2 + (size_t)row * DIM))[lane];

    auto wsum = [&](float v) -> float {
        #pragma unroll
        for (int m = 1; m < 64; m <<= 1) v += __shfl_xor(v, m, 64);
        return v;
    };

    const float na2 = wsum(a.x*a.x + a.y*a.y + a.z*a.z + a.w*a.w);
    const float nb2 = wsum(b.x*b.x + b.y*b.y + b.z*b.z + b.w*b.w);
    const float ia = 1.0f / sqrtf(na2);   // norms ~16; eps never binds
    const float ib = 1.0f / sqrtf(nb2);

    __hip_bfloat16 ah[4] = { __float2bfloat16(a.x*ia), __float2bfloat16(a.y*ia),
                             __float2bfloat16(a.z*ia), __float2bfloat16(a.w*ia) };
    __hip_bfloat16 bh[4] = { __float2bfloat16(b.x*ib), __float2bfloat16(b.y*ib),
                             __float2bfloat16(b.z*ib), __float2bfloat16(b.w*ib) };
    *(ushort4*)(Zn + (size_t)row * DIM + lane * 4) = *(ushort4*)ah;
    *(ushort4*)(Zn + (size_t)(N_ROWS + row) * DIM + lane * 4) = *(ushort4*)bh;

    float qd = 0.0f;
    #pragma unroll
    for (int k = 0; k < 4; ++k)
        qd += __bfloat162float(ah[k]) * __bfloat162float(bh[k]);
    qd = wsum(qd);
    if (lane == 0) pos[row] = qd;
}

// ---------------------------------------------------------------------------
// Kernel 2: symmetric gram of Z, upper triangle only, dense triangular grid.
// Block tile 128x128, wave tile 64x64 (4x4 frags), BK=64, 32 KB LDS,
// XOR-swizzled (0 conflicts measured). __launch_bounds__(256,4) targets
// <=128 unified regs -> 4 blocks/CU.
// TWO_STAGE: block stores 512 partial floats (row[2][128], col[2][128]) to a
// private ws slice — no atomics, no epilogue barrier. Fallback: atomics to S.
// ---------------------------------------------------------------------------
template <bool TWO_STAGE>
__global__ __launch_bounds__(256, 4) void gram_kernel(
    const __hip_bfloat16* __restrict__ Z,
    float* __restrict__ part, float* __restrict__ S)
{
    // decode triangular block index -> (ti, tj), tj >= ti
    const int bid = blockIdx.x;
    int ti = (int)((257.0f - sqrtf(66049.0f - 8.0f * (float)bid)) * 0.5f);
    while (ti * (257 - ti) / 2 > bid) --ti;
    while ((ti + 1) * (256 - ti) / 2 <= bid) ++ti;
    const int tj = ti + (bid - ti * (257 - ti) / 2);
    const bool diag = (ti == tj);

    __shared__ __hip_bfloat16 As[BT * BK];   // 16 KB
    __shared__ __hip_bfloat16 Bs[BT * BK];   // 16 KB

    const int tid  = threadIdx.x;
    const int wave = tid >> 6;
    const int lane = tid & 63;
    const int wr = wave >> 1;           // row half (0..1)
    const int wc = wave & 1;            // col half (0..1)
    const int lm = lane & 15;
    const int lq = lane >> 4;

    const int rowBase = ti * BT;
    const int colBase = tj * BT;

    // staging lane geometry: chunk = 8 rows x 8 groups of 16B (1 KB)
    const int srow  = lane >> 3;                // 0..7
    const int sgcol = ((lane & 7) ^ srow) << 3; // swizzled elem offset in row

    f32x4 acc[4][4] = {};

    for (int k0 = 0; k0 < DIM; k0 += BK) {
        if (k0) __syncthreads();        // protect LDS being read (prev iter)
        #pragma unroll
        for (int c = 0; c < 4; ++c) {   // A: 16 chunks, 4 per wave
            const int ch = wave * 4 + c;
            const int r = ch * 8 + srow;
            const __hip_bfloat16* ga = Z + (size_t)(rowBase + r) * DIM + k0 + sgcol;
            const __hip_bfloat16* gb = Z + (size_t)(colBase + r) * DIM + k0 + sgcol;
            __builtin_amdgcn_global_load_lds(
                (const __attribute__((address_space(1))) void*)ga,
                (__attribute__((address_space(3))) void*)(As + ch * 512),
                16, 0, 0);
            __builtin_amdgcn_global_load_lds(
                (const __attribute__((address_space(1))) void*)gb,
                (__attribute__((address_space(3))) void*)(Bs + ch * 512),
                16, 0, 0);
        }
        __syncthreads();

        #pragma unroll
        for (int kk = 0; kk < BK; kk += 32) {
            const int g = (kk >> 3) + lq;       // 16B group index
            bf16x8 af[4], bf[4];
            #pragma unroll
            for (int f = 0; f < 4; ++f) {
                const int ra = wr * 64 + f * 16 + lm;
                const int rb = wc * 64 + f * 16 + lm;
                af[f] = *(const bf16x8*)(As + ra * BK + ((g ^ (ra & 7)) << 3));
                bf[f] = *(const bf16x8*)(Bs + rb * BK + ((g ^ (rb & 7)) << 3));
            }
            #pragma unroll
            for (int fr = 0; fr < 4; ++fr)
                #pragma unroll
                for (int fc = 0; fc < 4; ++fc)
                    acc[fr][fc] = __builtin_amdgcn_mfma_f32_16x16x32_bf16(
                        af[fr], bf[fc], acc[fr][fc], 0, 0, 0);
        }
    }
    // no trailing barrier: epilogue is LDS-free

    // ---- epilogue: exp(2C), diagonal mask, partial row/col sums ----
    // C/D layout (m89/m91): col = lane&15, row = (lane>>4)*4 + reg
    #pragma unroll
    for (int fr = 0; fr < 4; ++fr)
        #pragma unroll
        for (int fc = 0; fc < 4; ++fc)
            #pragma unroll
            for (int r = 0; r < 4; ++r)
                acc[fr][fc][r] = __expf(acc[fr][fc][r] * TAU_INV);

    if (diag) {   // zero at-or-below-diagonal (each pair counted once)
        #pragma unroll
        for (int fr = 0; fr < 4; ++fr) {
            const int gi = wr * 64 + fr * 16 + lq * 4;
            #pragma unroll
            for (int fc = 0; fc < 4; ++fc) {
                const int gj = wc * 64 + fc * 16 + lm;
                #pragma unroll
                for (int r = 0; r < 4; ++r)
                    if (gj <= gi + r) acc[fr][fc][r] = 0.0f;
            }
        }
    }

    float* dst = TWO_STAGE ? (part + (size_t)bid * 512) : nullptr;

    // row partials: sum over this wave's 64 cols -> slot [wc][row 0..127]
    #pragma unroll
    for (int fr = 0; fr < 4; ++fr)
        #pragma unroll
        for (int r = 0; r < 4; ++r) {
            float s = acc[fr][0][r] + acc[fr][1][r] + acc[fr][2][r] + acc[fr][3][r];
            s += __shfl_xor(s, 1, 64);
            s += __shfl_xor(s, 2, 64);
            s += __shfl_xor(s, 4, 64);
            s += __shfl_xor(s, 8, 64);
            if (lm == 0) {
                const int rr = wr * 64 + fr * 16 + lq * 4 + r;
                if (TWO_STAGE) dst[wc * 128 + rr] = s;
                else atomicAdd(&S[rowBase + rr], s);
            }
        }
    // col partials: sum over this wave's 64 rows -> slot [wr][col 0..127]
    #pragma unroll
    for (int fc = 0; fc < 4; ++fc) {
        float s = 0.0f;
        #pragma unroll
        for (int fr = 0; fr < 4; ++fr)
            #pragma unroll
            for (int r = 0; r < 4; ++r) s += acc[fr][fc][r];
        s += __shfl_xor(s, 16, 64);
        s += __shfl_xor(s, 32, 64);
        if (lq == 0) {
            const int cc = wc * 64 + fc * 16 + lm;
            if (TWO_STAGE) dst[256 + wr * 128 + cc] = s;
            else atomicAdd(&S[colBase + cc], s);
        }
    }
}

// ---------------------------------------------------------------------------
// Kernel 3 (two-stage): sum partials for row i and row N+i, then loss + mean.
// Row r: tr=r>>7. Row-side: blocks (tr,tj) tj=tr..127; col-side: (ti,tr)
// ti=0..tr. All strip reads are 128-float coalesced.
// ---------------------------------------------------------------------------
__device__ __forceinline__ float sum_row_partials(const float* __restrict__ part,
                                                  int r)
{
    const int tr = r >> 7, rr = r & 127;
    float s = 0.0f;
    size_t b = (size_t)(tr * (257 - tr) / 2) * 512;     // block (tr,tr)
    for (int tj = tr; tj < 128; ++tj, b += 512)
        s += part[b + rr] + part[b + 128 + rr];
    for (int ti = 0; ti <= tr; ++ti) {
        const size_t bb = (size_t)(ti * (257 - ti) / 2 + tr - ti) * 512;
        s += part[bb + 256 + rr] + part[bb + 384 + rr];
    }
    return s;
}

__global__ __launch_bounds__(256) void reduce_loss_kernel(
    const float* __restrict__ part, const float* __restrict__ pos,
    float* __restrict__ out)
{
    const int i = blockIdx.x * 256 + threadIdx.x;   // 0..8191
    const float den1 = sum_row_partials(part, i);
    const float den2 = sum_row_partials(part, N_ROWS + i);
    float v = 0.5f * (logf(den1) + logf(den2)) - TAU_INV * pos[i];

    __shared__ float red[4];
    #pragma unroll
    for (int m = 1; m < 64; m <<= 1) v += __shfl_xor(v, m, 64);
    if ((threadIdx.x & 63) == 0) red[threadIdx.x >> 6] = v;
    __syncthreads();
    if (threadIdx.x == 0)
        atomicAdd(out, (red[0] + red[1] + red[2] + red[3]) * (1.0f / N_ROWS));
}

// Fallback loss (atomic path): S already holds diag-excluded sums.
__global__ __launch_bounds__(256) void loss_kernel(
    const float* __restrict__ S, const float* __restrict__ pos,
    float* __restrict__ out)
{
    const int i = blockIdx.x * 256 + threadIdx.x;
    float v = 0.5f * (logf(S[i]) + logf(S[N_ROWS + i])) - TAU_INV * pos[i];

    __shared__ float red[4];
    #pragma unroll
    for (int m = 1; m < 64; m <<= 1) v += __shfl_xor(v, m, 64);
    if ((threadIdx.x & 63) == 0) red[threadIdx.x >> 6] = v;
    __syncthreads();
    if (threadIdx.x == 0)
        atomicAdd(out, (red[0] + red[1] + red[2] + red[3]) * (1.0f / N_ROWS));
}

// ---------------------------------------------------------------------------
extern "C" void kernel_launch(void* const* d_in, const int* in_sizes, int n_in,
                              void* d_out, int out_size, void* d_ws, size_t ws_size,
                              hipStream_t stream)
{
    const float* z1 = (const float*)d_in[0];
    const float* z2 = (const float*)d_in[1];
    float* out = (float*)d_out;

    char* ws = (char*)d_ws;
    __hip_bfloat16* Zn = (__hip_bfloat16*)ws;            // 8 MB
    float* pos  = (float*)(ws + 8388608);                // 32 KB
    float* S    = (float*)(ws + 8421376);                // 64 KB
    float* part = (float*)(ws + 8486912);                // 8256*512*4 = 16.9 MB
    const size_t need = 8486912 + (size_t)NTRI * 512 * 4;

    hipMemsetAsync(out, 0, sizeof(float), stream);
    normalize_kernel<<<N_ROWS / 4, 256, 0, stream>>>(z1, z2, Zn, pos, S);

    if (ws_size >= need) {
        gram_kernel<true><<<NTRI, 256, 0, stream>>>(Zn, part, nullptr);
        reduce_loss_kernel<<<N_ROWS / 256, 256, 0, stream>>>(part, pos, out);
    } else {
        gram_kernel<false><<<NTRI, 256, 0, stream>>>(Zn, nullptr, S);
        loss_kernel<<<N_ROWS / 256, 256, 0, stream>>>(S, pos, out);
    }
}

// Round 6
// 195.900 us; speedup vs baseline: 1.1889x; 1.1889x over previous
//
#include <hip/hip_runtime.h>
#include <hip/hip_bf16.h>

#define N_ROWS 8192
#define NZ 16384           // rows of Z = [An; Bn]
#define DIM 256
#define TAU_INV 2.0f
#define BK 64
#define NTI 64             // 256-row tiles
#define NTJ 128            // 128-col tiles
#define NTRI 4160          // sum_{ti<64} (128 - 2*ti)
#define NCHUNK 16

typedef float f32x4 __attribute__((ext_vector_type(4)));
typedef short bf16x8 __attribute__((ext_vector_type(8)));

// ---------------------------------------------------------------------------
// Kernel 1: one WAVE per row. L2-normalize z1,z2 rows -> bf16 Zn (An rows
// 0..8191, Bn rows 8192..16383); pos[i] = dot of the QUANTIZED an_i,bn_i.
// Also zeroes Szero[0..16383] (only needed by the atomic fallback path).
// ---------------------------------------------------------------------------
__global__ __launch_bounds__(256) void normalize_kernel(
    const float* __restrict__ z1, const float* __restrict__ z2,
    __hip_bfloat16* __restrict__ Zn, float* __restrict__ pos,
    float* __restrict__ Szero)
{
    const int tid = threadIdx.x;
    if (blockIdx.x < 64) Szero[blockIdx.x * 256 + tid] = 0.0f;

    const int wave = tid >> 6;
    const int lane = tid & 63;
    const int row = blockIdx.x * 4 + wave;      // 0..8191

    const float4 a = ((const float4*)(z1 + (size_t)row * DIM))[lane];
    const float4 b = ((const float4*)(z2 + (size_t)row * DIM))[lane];

    auto wsum = [&](float v) -> float {
        #pragma unroll
        for (int m = 1; m < 64; m <<= 1) v += __shfl_xor(v, m, 64);
        return v;
    };

    const float na2 = wsum(a.x*a.x + a.y*a.y + a.z*a.z + a.w*a.w);
    const float nb2 = wsum(b.x*b.x + b.y*b.y + b.z*b.z + b.w*b.w);
    const float ia = 1.0f / sqrtf(na2);   // norms ~16; eps never binds
    const float ib = 1.0f / sqrtf(nb2);

    __hip_bfloat16 ah[4] = { __float2bfloat16(a.x*ia), __float2bfloat16(a.y*ia),
                             __float2bfloat16(a.z*ia), __float2bfloat16(a.w*ia) };
    __hip_bfloat16 bh[4] = { __float2bfloat16(b.x*ib), __float2bfloat16(b.y*ib),
                             __float2bfloat16(b.z*ib), __float2bfloat16(b.w*ib) };
    *(ushort4*)(Zn + (size_t)row * DIM + lane * 4) = *(ushort4*)ah;
    *(ushort4*)(Zn + (size_t)(N_ROWS + row) * DIM + lane * 4) = *(ushort4*)bh;

    float qd = 0.0f;
    #pragma unroll
    for (int k = 0; k < 4; ++k)
        qd += __bfloat162float(ah[k]) * __bfloat162float(bh[k]);
    qd = wsum(qd);
    if (lane == 0) pos[row] = qd;
}

// ---------------------------------------------------------------------------
// Kernel 2: symmetric gram of Z, upper triangle, 512-thread blocks.
// Block tile 256(rows) x 128(cols); 8 waves in 4x2; wave tile 64x64
// (4x4 frags of 16x16x32 bf16). BK=64, LDS 48 KB, XOR 16B-group swizzle
// (0 conflicts measured). __launch_bounds__(512,4) -> 128-reg cap ->
// 2 blocks/CU (16 waves = 50%).
// Triangle: tiles (ti,tj) with tj >= 2*ti; diag-crossing (tj>>1==ti) masks
// gj <= gi after exp. TWO_STAGE: 1024 partial floats per block to ws
// ([0..511] rowslots wc*256+rr, [512..1023] colslots wr*128+cc), no atomics.
// ---------------------------------------------------------------------------
template <bool TWO_STAGE>
__global__ __launch_bounds__(512, 4) void gram_kernel(
    const __hip_bfloat16* __restrict__ Z,
    float* __restrict__ part, float* __restrict__ S)
{
    // XCD band remap (4160 = 8 * 520), then triangular decode.
    const int bid = (blockIdx.x & 7) * (NTRI / 8) + (blockIdx.x >> 3);
    // P(ti) = ti*(129-ti); find ti with P(ti) <= bid < P(ti+1)
    int ti = (int)((129.0f - sqrtf(16641.0f - 4.0f * (float)bid)) * 0.5f);
    ti = ti < 0 ? 0 : (ti > 63 ? 63 : ti);
    while (ti * (129 - ti) > bid) --ti;
    while ((ti + 1) * (128 - ti) <= bid) ++ti;
    const int tj = 2 * ti + (bid - ti * (129 - ti));
    const bool diag = ((tj >> 1) == ti);

    __shared__ __hip_bfloat16 As[256 * BK];   // 32 KB
    __shared__ __hip_bfloat16 Bs[128 * BK];   // 16 KB

    const int tid  = threadIdx.x;
    const int wave = tid >> 6;          // 0..7
    const int lane = tid & 63;
    const int wr = wave >> 1;           // 0..3 (64-row band)
    const int wc = wave & 1;            // 0..1 (64-col band)
    const int lm = lane & 15;
    const int lq = lane >> 4;

    const int rowBase = ti * 256;
    const int colBase = tj * 128;

    // staging: chunk = 8 rows x 8 groups of 16B (1 KB); LDS[r][g]=glob[r][g^(r&7)]
    const int srow  = lane >> 3;
    const int sgcol = ((lane & 7) ^ srow) << 3;

    f32x4 acc[4][4] = {};

    for (int k0 = 0; k0 < DIM; k0 += BK) {
        if (k0) __syncthreads();
        #pragma unroll
        for (int c = 0; c < 4; ++c) {           // A: 32 chunks, 4 per wave
            const int ch = wave * 4 + c;
            const int r = ch * 8 + srow;
            const __hip_bfloat16* ga = Z + (size_t)(rowBase + r) * DIM + k0 + sgcol;
            __builtin_amdgcn_global_load_lds(
                (const __attribute__((address_space(1))) void*)ga,
                (__attribute__((address_space(3))) void*)(As + ch * 512),
                16, 0, 0);
        }
        #pragma unroll
        for (int c = 0; c < 2; ++c) {           // B: 16 chunks, 2 per wave
            const int ch = wave * 2 + c;
            const int r = ch * 8 + srow;
            const __hip_bfloat16* gb = Z + (size_t)(colBase + r) * DIM + k0 + sgcol;
            __builtin_amdgcn_global_load_lds(
                (const __attribute__((address_space(1))) void*)gb,
                (__attribute__((address_space(3))) void*)(Bs + ch * 512),
                16, 0, 0);
        }
        __syncthreads();

        #pragma unroll
        for (int kk = 0; kk < BK; kk += 32) {
            const int g = (kk >> 3) + lq;
            bf16x8 af[4], bf[4];
            #pragma unroll
            for (int f = 0; f < 4; ++f) {
                const int ra = wr * 64 + f * 16 + lm;
                const int rb = wc * 64 + f * 16 + lm;
                af[f] = *(const bf16x8*)(As + ra * BK + ((g ^ (ra & 7)) << 3));
                bf[f] = *(const bf16x8*)(Bs + rb * BK + ((g ^ (rb & 7)) << 3));
            }
            #pragma unroll
            for (int fr = 0; fr < 4; ++fr)
                #pragma unroll
                for (int fc = 0; fc < 4; ++fc)
                    acc[fr][fc] = __builtin_amdgcn_mfma_f32_16x16x32_bf16(
                        af[fr], bf[fc], acc[fr][fc], 0, 0, 0);
        }
    }
    // epilogue is LDS-free: no trailing barrier

    // exp(2c) = exp2(c * 2*log2(e)); C/D layout: col=lane&15, row=lq*4+reg
    const float SC = 2.8853900817779268f;
    #pragma unroll
    for (int fr = 0; fr < 4; ++fr)
        #pragma unroll
        for (int fc = 0; fc < 4; ++fc)
            #pragma unroll
            for (int r = 0; r < 4; ++r)
                acc[fr][fc][r] = exp2f(acc[fr][fc][r] * SC);

    if (diag) {   // zero at-or-below-diagonal (each pair counted once)
        #pragma unroll
        for (int fr = 0; fr < 4; ++fr) {
            const int gi = rowBase + wr * 64 + fr * 16 + lq * 4;
            #pragma unroll
            for (int fc = 0; fc < 4; ++fc) {
                const int gj = colBase + wc * 64 + fc * 16 + lm;
                #pragma unroll
                for (int r = 0; r < 4; ++r)
                    if (gj <= gi + r) acc[fr][fc][r] = 0.0f;
            }
        }
    }

    float* dst = TWO_STAGE ? (part + (size_t)bid * 1024) : nullptr;

    // row partials over this wave's 64 cols -> slot [wc][0..255]
    #pragma unroll
    for (int fr = 0; fr < 4; ++fr)
        #pragma unroll
        for (int r = 0; r < 4; ++r) {
            float s = acc[fr][0][r] + acc[fr][1][r] + acc[fr][2][r] + acc[fr][3][r];
            s += __shfl_xor(s, 1, 64);
            s += __shfl_xor(s, 2, 64);
            s += __shfl_xor(s, 4, 64);
            s += __shfl_xor(s, 8, 64);
            if (lm == 0) {
                const int rr = wr * 64 + fr * 16 + lq * 4 + r;
                if (TWO_STAGE) dst[wc * 256 + rr] = s;
                else atomicAdd(&S[rowBase + rr], s);
            }
        }
    // col partials over this wave's 64 rows -> slot [wr][0..127]
    #pragma unroll
    for (int fc = 0; fc < 4; ++fc) {
        float s = 0.0f;
        #pragma unroll
        for (int fr = 0; fr < 4; ++fr)
            #pragma unroll
            for (int r = 0; r < 4; ++r) s += acc[fr][fc][r];
        s += __shfl_xor(s, 16, 64);
        s += __shfl_xor(s, 32, 64);
        if (lq == 0) {
            const int cc = wc * 64 + fc * 16 + lm;
            if (TWO_STAGE) dst[512 + wr * 128 + cc] = s;
            else atomicAdd(&S[colBase + cc], s);
        }
    }
}

// ---------------------------------------------------------------------------
// Kernel 3: parallel partial-sum gather. grid (64 row-tiles, NCHUNK).
// Every Z-row has exactly 260 contributions:
//   row-side: blocks (tr2, tj) tj=2*tr2..127, slots {0,256}+rr   (2*(128-2tr2))
//   col-side: blocks (ti, tc)  ti=0..tr2,    slots 512+wr*128+cc (4*(tr2+1))
// All loads coalesced (consecutive threads -> consecutive rr/cc).
// ---------------------------------------------------------------------------
__global__ __launch_bounds__(256) void reduce_kernel(
    const float* __restrict__ part, float* __restrict__ S2)
{
    const int chunk = blockIdx.y;
    const int tid = threadIdx.x;
    const int tr2 = blockIdx.x;                 // 256-row tile
    const int r = tr2 * 256 + tid;              // Z row
    const int rr = tid;
    const int tc = r >> 7;
    const int cc = r & 127;
    const int cnt1 = 2 * (128 - 2 * tr2);

    float s = 0.0f;
    for (int m = chunk; m < 260; m += NCHUNK) {
        size_t addr;
        if (m < cnt1) {
            const int tj = 2 * tr2 + (m >> 1);
            const int bb = tr2 * (129 - tr2) + tj - 2 * tr2;
            addr = (size_t)bb * 1024 + (m & 1) * 256 + rr;
        } else {
            const int m2 = m - cnt1;
            const int ti = m2 >> 2;
            const int bb = ti * (129 - ti) + tc - 2 * ti;
            addr = (size_t)bb * 1024 + 512 + (m2 & 3) * 128 + cc;
        }
        s += part[addr];
    }
    S2[(size_t)chunk * NZ + r] = s;
}

// ---------------------------------------------------------------------------
// Kernel 4: loss + mean (two-stage path).
// ---------------------------------------------------------------------------
__global__ __launch_bounds__(256) void loss2_kernel(
    const float* __restrict__ S2, const float* __restrict__ pos,
    float* __restrict__ out)
{
    const int i = blockIdx.x * 256 + threadIdx.x;
    float den1 = 0.0f, den2 = 0.0f;
    #pragma unroll
    for (int c = 0; c < NCHUNK; ++c) {
        den1 += S2[(size_t)c * NZ + i];
        den2 += S2[(size_t)c * NZ + N_ROWS + i];
    }
    float v = 0.5f * (logf(den1) + logf(den2)) - TAU_INV * pos[i];

    __shared__ float red[4];
    #pragma unroll
    for (int m = 1; m < 64; m <<= 1) v += __shfl_xor(v, m, 64);
    if ((threadIdx.x & 63) == 0) red[threadIdx.x >> 6] = v;
    __syncthreads();
    if (threadIdx.x == 0)
        atomicAdd(out, (red[0] + red[1] + red[2] + red[3]) * (1.0f / N_ROWS));
}

// Fallback loss (atomic path): S holds diag-excluded sums directly.
__global__ __launch_bounds__(256) void loss_kernel(
    const float* __restrict__ S, const float* __restrict__ pos,
    float* __restrict__ out)
{
    const int i = blockIdx.x * 256 + threadIdx.x;
    float v = 0.5f * (logf(S[i]) + logf(S[N_ROWS + i])) - TAU_INV * pos[i];

    __shared__ float red[4];
    #pragma unroll
    for (int m = 1; m < 64; m <<= 1) v += __shfl_xor(v, m, 64);
    if ((threadIdx.x & 63) == 0) red[threadIdx.x >> 6] = v;
    __syncthreads();
    if (threadIdx.x == 0)
        atomicAdd(out, (red[0] + red[1] + red[2] + red[3]) * (1.0f / N_ROWS));
}

// ---------------------------------------------------------------------------
extern "C" void kernel_launch(void* const* d_in, const int* in_sizes, int n_in,
                              void* d_out, int out_size, void* d_ws, size_t ws_size,
                              hipStream_t stream)
{
    const float* z1 = (const float*)d_in[0];
    const float* z2 = (const float*)d_in[1];
    float* out = (float*)d_out;

    char* ws = (char*)d_ws;
    __hip_bfloat16* Zn = (__hip_bfloat16*)ws;            // 8 MB
    float* pos  = (float*)(ws + 8388608);                // 32 KB
    float* S2   = (float*)(ws + 8421376);                // 16*16384*4 = 1 MB
    float* part = (float*)(ws + 9469952);                // 4160*1024*4 = 16.25 MB
    const size_t need = 9469952 + (size_t)NTRI * 1024 * 4;

    hipMemsetAsync(out, 0, sizeof(float), stream);
    // normalize also zeroes S2[0..16383] (atomic-fallback accumulator)
    normalize_kernel<<<N_ROWS / 4, 256, 0, stream>>>(z1, z2, Zn, pos, S2);

    if (ws_size >= need) {
        gram_kernel<true><<<NTRI, 512, 0, stream>>>(Zn, part, nullptr);
        dim3 rg(NZ / 256, NCHUNK);
        reduce_kernel<<<rg, 256, 0, stream>>>(part, S2);
        loss2_kernel<<<N_ROWS / 256, 256, 0, stream>>>(S2, pos, out);
    } else {
        gram_kernel<false><<<NTRI, 512, 0, stream>>>(Zn, nullptr, S2);
        loss_kernel<<<N_ROWS / 256, 256, 0, stream>>>(S2, pos, out);
    }
}